// Round 8
// baseline (1583.664 us; speedup 1.0000x reference)
//
#include <hip/hip_runtime.h>
#include <stdint.h>

#define BATCH 512
#define TMAX 1024
#define DIN 4
#define H 64
#define NC 1098
#define RCH 32   // rec kernel: h0 rows staged in LDS per chunk (power of 2)

typedef __attribute__((ext_vector_type(2))) float v2;

__device__ __forceinline__ v2 mkv2(float a, float b) { v2 r; r.x = a; r.y = b; return r; }

__device__ __forceinline__ float sigmoidf_(float x) {
    return 1.0f / (1.0f + __expf(-x));
}
__device__ __forceinline__ float tanhf_(float x) {
    return 1.0f - 2.0f / (__expf(2.0f * x) + 1.0f);
}
// broadcast lane k of h to all lanes via v_readlane (SGPR path, zero DS ops)
__device__ __forceinline__ float rdlane(float v, int k) {
    return __int_as_float(__builtin_amdgcn_readlane(__float_as_int(v), k));
}
// bf16 helpers (RNE)
__device__ __forceinline__ uint32_t f2bf(float f) {
    uint32_t u = __float_as_uint(f);
    return (u + 0x7FFFu + ((u >> 16) & 1u)) >> 16;
}
__device__ __forceinline__ float bf2f(uint32_t h) {
    return __uint_as_float(h << 16);
}

// ============ Layer 0: 2-wave gate split, register h, readlane matvec =======
// Wave 0 owns gates {i,f} of h-index j=lane, wave 1 owns {g,o}. h lives in a
// REGISTER (lane k holds h_k; both waves update redundantly) — the Whh matvec
// uses v_readlane broadcasts + v_pk_fma on (rowA,rowB)-packed weights, so the
// per-step LDS traffic is just one b64 exchange write+read. R7 was DS-pipe
// bound (~35 DS instr/step/unit x 4 units/CU ~ 1500 cyc/step on one LDS pipe).
__global__ __launch_bounds__(128) void lstm_layer0_rl(
    const float* __restrict__ x, const int* __restrict__ lengths,
    const float* __restrict__ Wih_f, const float* __restrict__ Whh_f,
    const float* __restrict__ bih_f, const float* __restrict__ bhh_f,
    const float* __restrict__ Wih_b, const float* __restrict__ Whh_b,
    const float* __restrict__ bih_b, const float* __restrict__ bhh_b,
    uint16_t* __restrict__ h0b /* [B, T, 2H] bf16 */)
{
    const int unit = blockIdx.x;
    const int b = unit >> 1, dir = unit & 1;
    const int t = threadIdx.x;
    const int j = t & 63, w = t >> 6;   // w in {0,1}
    const int L = lengths[b];

    const float* Wih = dir ? Wih_b : Wih_f;
    const float* Whh = dir ? Whh_b : Whh_f;
    const float* bih = dir ? bih_b : bih_f;
    const float* bhh = dir ? bhh_b : bhh_f;

    const int rA = (2*w) * H + j;       // wave0: i ; wave1: g
    const int rB = (2*w + 1) * H + j;   // wave0: f ; wave1: o

    v2 whh2[H];                          // whh2[k] = (WhhA[k], WhhB[k])
    {
        const float4* pa = (const float4*)(Whh + (size_t)rA * H);
        const float4* pb = (const float4*)(Whh + (size_t)rB * H);
        #pragma unroll
        for (int k = 0; k < 16; k++) {
            float4 va = pa[k], vb = pb[k];
            whh2[4*k+0] = mkv2(va.x, vb.x);
            whh2[4*k+1] = mkv2(va.y, vb.y);
            whh2[4*k+2] = mkv2(va.z, vb.z);
            whh2[4*k+3] = mkv2(va.w, vb.w);
        }
    }
    const float4 wxA = ((const float4*)Wih)[rA];
    const float4 wxB = ((const float4*)Wih)[rB];
    const float bA = bih[rA] + bhh[rA];
    const float bB = bih[rB] + bhh[rB];

    __shared__ __align__(16) float4 xbuf4[TMAX];  // 16 KB: whole x[b]
    __shared__ __align__(16) float hist[32 * H];  // 8 KB: h ring (wave0)
    __shared__ __align__(16) v2 ex2[2][2][H];     // parity gate exchange (b64)

    {
        const float4* x4 = (const float4*)x + (size_t)b * TMAX;
        for (int i = t; i < L; i += 128) xbuf4[i] = x4[i];
    }
    float c = 0.0f, h = 0.0f;           // register state: lane j holds c_j,h_j
    __syncthreads();

    for (int s = 0; s < L; s++) {
        const int tt = dir ? (L - 1 - s) : s;
        const float4 xt = xbuf4[tt];              // uniform -> broadcast

        float aA = bA, aB = bB;                   // xW (DIN=4, scalar)
        aA = fmaf(wxA.x, xt.x, aA); aA = fmaf(wxA.y, xt.y, aA);
        aA = fmaf(wxA.z, xt.z, aA); aA = fmaf(wxA.w, xt.w, aA);
        aB = fmaf(wxB.x, xt.x, aB); aB = fmaf(wxB.y, xt.y, aB);
        aB = fmaf(wxB.z, xt.z, aB); aB = fmaf(wxB.w, xt.w, aB);

        // Whh matvec via readlane broadcast: zero DS, pure VALU
        v2 acc0 = mkv2(aA, aB), acc1 = mkv2(0.0f, 0.0f);
        #pragma unroll
        for (int k = 0; k < H; k += 2) {
            const float hk0 = rdlane(h, k);
            const float hk1 = rdlane(h, k + 1);
            acc0 += whh2[k]     * mkv2(hk0, hk0);
            acc1 += whh2[k + 1] * mkv2(hk1, hk1);
        }
        const v2 accs = acc0 + acc1;
        const float actA = (w == 1) ? tanhf_(accs.x) : sigmoidf_(accs.x);
        const float actB = sigmoidf_(accs.y);
        const int p = s & 1;
        ex2[p][w][j] = mkv2(actA, actB);          // b64, 2 lanes/bank (free)
        __syncthreads();                          // the ONLY per-step barrier
        const v2 other = ex2[p][1 - w][j];
        const float gi = w ? other.x : actA;
        const float gf = w ? other.y : actB;
        const float gg = w ? actA : other.x;
        const float go = w ? actB : other.y;
        c = fmaf(gf, c, gi * gg);
        h = go * tanhf_(c);
        if (w == 0) {
            hist[(s & 31) * H + j] = h;
            if ((s & 31) == 31 || s == L - 1) {   // flush (0 conflicts R6/R7)
                const int s0c = s & ~31, nrows = s - s0c + 1;
                const int jc = j & 31, jr = j >> 5;
                for (int base = 0; base + jr < nrows; base += 2) {
                    const int rr = base + jr;
                    const int t2 = dir ? (L - 1 - (s0c + rr)) : (s0c + rr);
                    const float2 hv = *(const float2*)(hist + rr * H + jc * 2);
                    const uint32_t pk = f2bf(hv.x) | (f2bf(hv.y) << 16);
                    *(uint32_t*)(h0b + ((size_t)b * TMAX + t2) * (2*H) + dir * H + jc * 2) = pk;
                }
            }
        }
    }
}

// ====== Layer 1: producer/consumer pipeline, register h, readlane matvec ====
// 512 threads. Waves 0-3 (producers) compute xW partials for step s+1 (wave w
// owns k-slice [32w,32w+32), lane j owns gates 4j..4j+3; 8 b128 broadcasts +
// 1 b128 write) — unchanged from R7. Waves 4-7 (consumers) own gate row
// (w-4)*64+j; h now lives in a REGISTER per consumer wave (lane k holds h_k,
// updated redundantly), and the serial Whh dot is a readlane matvec — the 64
// hrep b128 broadcasts/step that made R7 DS-bound are GONE. One barrier/step.
__global__ __launch_bounds__(512) void lstm_rec_rl(
    const uint16_t* __restrict__ h0b, const int* __restrict__ lengths,
    const float* __restrict__ Wih, const float* __restrict__ Whh,
    const float* __restrict__ bih, const float* __restrict__ bhh,
    const float* __restrict__ Wih_b,
    const float* __restrict__ bih_b, const float* __restrict__ bhh_b,
    const float* __restrict__ Wout, const float* __restrict__ bout,
    float* __restrict__ out)
{
    const int b = blockIdx.x;
    const int t = threadIdx.x;
    const int j = t & 63, w = t >> 6;   // w in 0..7
    const int L = lengths[b];
    const bool isProd = (w < 4);

    __shared__ __align__(16) float xch[RCH * 128];   // 16 KB: fp32 h0 rows
    __shared__ __align__(16) float part[2][4][256];  // 8 KB: xW partials
    __shared__ __align__(16) float ex[2][4][H];      // parity gate exchange
    __shared__ __align__(16) float ybuf[2*H];

    v2 wreg[64];                         // producers: 128 wih floats
    float whh[H];                        // consumers: 64 whh floats
    float bias = 0.0f;
    if (isProd) {
        #pragma unroll
        for (int q = 0; q < 4; q++) {
            const float4* pw = (const float4*)(Wih + (size_t)(4*j + q) * 128 + 32 * w);
            #pragma unroll
            for (int k = 0; k < 8; k++) {
                float4 v = pw[k];
                wreg[q*16 + 2*k]     = mkv2(v.x, v.y);
                wreg[q*16 + 2*k + 1] = mkv2(v.z, v.w);
            }
        }
    } else {
        const int g = (w - 4) * H + j;
        const float4* pw = (const float4*)(Whh + (size_t)g * H);
        #pragma unroll
        for (int k = 0; k < 16; k++) {
            float4 v = pw[k];
            whh[4*k+0] = v.x; whh[4*k+1] = v.y;
            whh[4*k+2] = v.z; whh[4*k+3] = v.w;
        }
        bias = bih[g] + bhh[g];
    }
    float c = 0.0f, h = 0.0f;           // consumer register state (lane j)

    auto produce = [&](int r, int p) {
        const float4* xr = (const float4*)(xch + r * 128 + 32 * w);
        v2 a0 = mkv2(0,0), a1 = mkv2(0,0), a2 = mkv2(0,0), a3 = mkv2(0,0);
        #pragma unroll
        for (int k = 0; k < 8; k++) {
            float4 xv = xr[k];                    // broadcast b128
            v2 xlo = mkv2(xv.x, xv.y), xhi = mkv2(xv.z, xv.w);
            a0 += wreg[ 0 + 2*k] * xlo; a0 += wreg[ 0 + 2*k + 1] * xhi;
            a1 += wreg[16 + 2*k] * xlo; a1 += wreg[16 + 2*k + 1] * xhi;
            a2 += wreg[32 + 2*k] * xlo; a2 += wreg[32 + 2*k + 1] * xhi;
            a3 += wreg[48 + 2*k] * xlo; a3 += wreg[48 + 2*k + 1] * xhi;
        }
        *(float4*)&part[p][w][4*j] =
            make_float4(a0.x + a0.y, a1.x + a1.y, a2.x + a2.y, a3.x + a3.y);
    };

    for (int s = 0; s < L; s++) {
        const int rr = s & (RCH - 1);
        if (rr == 0) {
            __syncthreads();                      // xch reuse safety
            const uint32_t* src = (const uint32_t*)(h0b + ((size_t)b * TMAX + s) * (2*H));
            for (int i = t; i < RCH * 64; i += 512) {
                uint32_t u = src[i];
                *(float2*)(xch + 2*i) = make_float2(bf2f(u & 0xFFFFu), bf2f(u >> 16));
            }
            __syncthreads();
            if (isProd) produce(0, s & 1);        // boundary row s
            __syncthreads();
        }
        if (isProd) {
            if (s + 1 < L && rr + 1 < RCH)        // lookahead: row s+1
                produce(rr + 1, (s + 1) & 1);
        } else {
            const int g = (w - 4) * H + j;
            const float pa = part[s & 1][0][g] + part[s & 1][1][g]
                           + part[s & 1][2][g] + part[s & 1][3][g];
            // serial Whh dot: readlane broadcast of register h, zero DS
            float a0 = pa + bias, a1 = 0.0f, a2 = 0.0f, a3 = 0.0f;
            #pragma unroll
            for (int k = 0; k < H; k += 4) {
                const float h0r = rdlane(h, k);
                const float h1r = rdlane(h, k + 1);
                const float h2r = rdlane(h, k + 2);
                const float h3r = rdlane(h, k + 3);
                a0 = fmaf(whh[k],     h0r, a0);
                a1 = fmaf(whh[k + 1], h1r, a1);
                a2 = fmaf(whh[k + 2], h2r, a2);
                a3 = fmaf(whh[k + 3], h3r, a3);
            }
            const float a = (a0 + a1) + (a2 + a3);
            ex[s & 1][w - 4][j] = (w == 6) ? tanhf_(a) : sigmoidf_(a);
        }
        __syncthreads();                          // the per-step barrier
        if (!isProd) {
            const int p = s & 1;
            const float gi = ex[p][0][j], gf = ex[p][1][j];
            const float gg = ex[p][2][j], go = ex[p][3][j];
            c = fmaf(gf, c, gi * gg);
            h = go * tanhf_(c);
        }
    }

    // ---- epilogue: y = [h1f_last, h1b_first]; logits = y @ Wout^T + bout ---
    if (w == 4) ybuf[j] = h;                      // fwd last h
    __syncthreads();
    const float* xrow = xch + ((L - 1) & (RCH - 1)) * 128;  // h0 row L-1, fp32
    float* gb = &part[0][0][0];
    if (t < 256) {  // bwd first step, zero state -> Whh_l1b unused
        const float4* wb = (const float4*)(Wih_b + (size_t)t * 128);
        const float4* xv = (const float4*)xrow;
        v2 a0 = mkv2(bih_b[t] + bhh_b[t], 0.0f), a1 = mkv2(0.0f, 0.0f);
        #pragma unroll
        for (int k = 0; k < 32; k++) {
            float4 wv = wb[k], xk = xv[k];
            a0 += mkv2(wv.x, wv.y) * mkv2(xk.x, xk.y);
            a1 += mkv2(wv.z, wv.w) * mkv2(xk.z, xk.w);
        }
        const float a = (a0.x + a0.y) + (a1.x + a1.y);
        gb[t] = (t >= 128 && t < 192) ? tanhf_(a) : sigmoidf_(a);
    }
    __syncthreads();
    if (t < 64) {
        const float gi = gb[t], gg = gb[128 + t], go = gb[192 + t];
        ybuf[H + t] = go * tanhf_(gi * gg);       // c_prev = 0, f unused
    }
    __syncthreads();

    const float4* yv = (const float4*)ybuf;
    for (int o = t; o < NC; o += 512) {
        const float4* wr = (const float4*)(Wout + (size_t)o * (2*H));
        v2 a0 = mkv2(bout[o], 0.0f), a1 = mkv2(0.0f, 0.0f);
        #pragma unroll
        for (int k = 0; k < 32; k++) {
            float4 wv = wr[k], yy = yv[k];
            a0 += mkv2(wv.x, wv.y) * mkv2(yy.x, yy.y);
            a1 += mkv2(wv.z, wv.w) * mkv2(yy.z, yy.w);
        }
        out[(size_t)b * NC + o] = (a0.x + a0.y) + (a1.x + a1.y);
    }
}

extern "C" void kernel_launch(void* const* d_in, const int* in_sizes, int n_in,
                              void* d_out, int out_size, void* d_ws, size_t ws_size,
                              hipStream_t stream) {
    const float* x        = (const float*)d_in[0];
    const int*   lengths  = (const int*)  d_in[1];
    const float* Wih_l0f  = (const float*)d_in[2];
    const float* Whh_l0f  = (const float*)d_in[3];
    const float* bih_l0f  = (const float*)d_in[4];
    const float* bhh_l0f  = (const float*)d_in[5];
    const float* Wih_l0b  = (const float*)d_in[6];
    const float* Whh_l0b  = (const float*)d_in[7];
    const float* bih_l0b  = (const float*)d_in[8];
    const float* bhh_l0b  = (const float*)d_in[9];
    const float* Wih_l1f  = (const float*)d_in[10];
    const float* Whh_l1f  = (const float*)d_in[11];
    const float* bih_l1f  = (const float*)d_in[12];
    const float* bhh_l1f  = (const float*)d_in[13];
    const float* Wih_l1b  = (const float*)d_in[14];
    // d_in[15] = Whh_l1b: unused (backward dir only needs its first step, h=0)
    const float* bih_l1b  = (const float*)d_in[16];
    const float* bhh_l1b  = (const float*)d_in[17];
    const float* Wout     = (const float*)d_in[18];
    const float* bout     = (const float*)d_in[19];
    float* out = (float*)d_out;

    // ws: h0 bf16 [B,T,2H] = 128 MiB
    uint16_t* h0b = (uint16_t*)d_ws;

    lstm_layer0_rl<<<dim3(2 * BATCH), 128, 0, stream>>>(
        x, lengths,
        Wih_l0f, Whh_l0f, bih_l0f, bhh_l0f,
        Wih_l0b, Whh_l0b, bih_l0b, bhh_l0b, h0b);

    lstm_rec_rl<<<dim3(BATCH), 512, 0, stream>>>(
        h0b, lengths,
        Wih_l1f, Whh_l1f, bih_l1f, bhh_l1f,
        Wih_l1b, bih_l1b, bhh_l1b, Wout, bout, out);
}